// Round 12
// baseline (422.971 us; speedup 1.0000x reference)
//
#include <hip/hip_runtime.h>
#include <hip/hip_bf16.h>
#include <hip/hip_cooperative_groups.h>

namespace cg = cooperative_groups;

#define BATCH 16
#define D_OUT 1024
#define D_HID 512
#define D_FLT 13824
#define N0Q 9216
#define TW 14
#define TH 16
#define NTX 19
#define NB 2

typedef __attribute__((ext_vector_type(8))) short bf16x8;
typedef __attribute__((ext_vector_type(4))) float f32x4;

__device__ __forceinline__ float lrelu(float x) { return x >= 0.f ? x : 0.2f * x; }
__device__ __forceinline__ ushort f2bf(float x) {
  unsigned u = __float_as_uint(x);
  u += 0x7FFFu + ((u >> 16) & 1u);
  return (ushort)(u >> 16);
}

// ONE cooperative kernel for the whole filter pipeline (was 3-4 launches):
// phase 1: tex transpose (blocks 128..383) || fc1 (blocks 0..127)
// phase 2: fc2 (blocks 0..127)
// phase 3: fc3 + permute + bf16 (all 864 blocks, 4 j per wave)
// No LDS: z/h1/h2 are tiny and L2-hot; avoids R11's occupancy trap.
__global__ __launch_bounds__(256, 4) void mlp_coop(const float* __restrict__ z,
                                                   const float* __restrict__ tex,
                                                   const float* __restrict__ W1,
                                                   const float* __restrict__ b1,
                                                   const float* __restrict__ W2,
                                                   const float* __restrict__ b2,
                                                   const float* __restrict__ W3,
                                                   const float* __restrict__ b3,
                                                   float* __restrict__ h1,
                                                   float* __restrict__ h2,
                                                   ushort* __restrict__ wbf,
                                                   ushort* __restrict__ texT) {
  cg::grid_group grid = cg::this_grid();
  const int tid = threadIdx.x, bid = blockIdx.x;
  const int w = tid >> 6, lane = tid & 63;

  // ---- phase 1 ----
  if (bid >= 128 && bid < 384) {
    // tex fp32 [32][256][256] -> bf16 pixel-major [256*256][32]
    int p = (bid - 128) * 256 + tid;
    unsigned pk[16];
    #pragma unroll
    for (int i = 0; i < 16; ++i) {
      ushort lo = f2bf(tex[(2 * i) * 65536 + p]);
      ushort hi = f2bf(tex[(2 * i + 1) * 65536 + p]);
      pk[i] = (unsigned)lo | ((unsigned)hi << 16);
    }
    uint4* dst = (uint4*)&texT[(size_t)p * 32];
    #pragma unroll
    for (int qq = 0; qq < 4; ++qq) {
      uint4 v; v.x = pk[qq * 4]; v.y = pk[qq * 4 + 1]; v.z = pk[qq * 4 + 2]; v.w = pk[qq * 4 + 3];
      dst[qq] = v;
    }
  } else if (bid < 128) {
    // fc1: wave per j, all 16 batches per W1-element read
    int j = bid * 4 + w;
    float acc[BATCH];
    #pragma unroll
    for (int b = 0; b < BATCH; ++b) acc[b] = 0.f;
    for (int k = lane; k < D_OUT; k += 64) {
      float wv = W1[j * D_OUT + k];
      #pragma unroll
      for (int b = 0; b < BATCH; ++b) acc[b] += wv * z[b * D_OUT + k];
    }
    #pragma unroll
    for (int b = 0; b < BATCH; ++b) {
      #pragma unroll
      for (int off = 32; off; off >>= 1) acc[b] += __shfl_xor(acc[b], off);
    }
    if (lane == 0) {
      float bb = b1[j];
      #pragma unroll
      for (int b = 0; b < BATCH; ++b) h1[b * D_HID + j] = lrelu(acc[b] + bb);
    }
  }
  __threadfence();
  grid.sync();

  // ---- phase 2: fc2 ----
  if (bid < 128) {
    int j = bid * 4 + w;
    float acc[BATCH];
    #pragma unroll
    for (int b = 0; b < BATCH; ++b) acc[b] = 0.f;
    for (int k = lane; k < D_HID; k += 64) {
      float wv = W2[j * D_HID + k];
      #pragma unroll
      for (int b = 0; b < BATCH; ++b) acc[b] += wv * h1[b * D_HID + k];
    }
    #pragma unroll
    for (int b = 0; b < BATCH; ++b) {
      #pragma unroll
      for (int off = 32; off; off >>= 1) acc[b] += __shfl_xor(acc[b], off);
    }
    if (lane == 0) {
      float bb = b2[j];
      #pragma unroll
      for (int b = 0; b < BATCH; ++b) h2[b * D_HID + j] = lrelu(acc[b] + bb);
    }
  }
  __threadfence();
  grid.sync();

  // ---- phase 3: fc3, 4 j per wave ----
  #pragma unroll 1
  for (int jj = 0; jj < 4; ++jj) {
    int j = bid * 16 + w * 4 + jj;
    float acc[BATCH];
    #pragma unroll
    for (int b = 0; b < BATCH; ++b) acc[b] = 0.f;
    for (int k = lane; k < D_HID; k += 64) {
      float wv = W3[(size_t)j * D_HID + k];
      #pragma unroll
      for (int b = 0; b < BATCH; ++b) acc[b] += wv * h2[b * D_HID + k];
    }
    #pragma unroll
    for (int b = 0; b < BATCH; ++b) {
      #pragma unroll
      for (int off = 32; off; off >>= 1) acc[b] += __shfl_xor(acc[b], off);
    }
    if (lane == 0) {
      float bb = b3[j];
      int dst;
      if (j < N0Q) {
        int co = j / 288, rem = j - co * 288;
        int ci = rem / 9, kp = rem - ci * 9;
        dst = kp * 1024 + co * 32 + ci;
      } else {
        int t = j - N0Q;
        int co = t / 288, rem = t - co * 288;
        int ci = rem / 9, kp = rem - ci * 9;
        dst = N0Q + kp * 512 + co * 32 + ci;
      }
      #pragma unroll
      for (int b = 0; b < BATCH; ++b) wbf[(size_t)b * D_FLT + dst] = f2bf(acc[b] + bb);
    }
  }
}

// Fused conv1(32->32,3x3,lrelu)+conv2(32->16,3x3), MFMA 16x16x32 bf16.
// Block = 14x16 tile x NB=2 batches. Sliding-window rows (B-reads halved,
// 10/4 independent MFMA chains). (256,2): full VGPR budget, no spill (R11:
// VGPR 104, WRITE_SIZE clean 94MB). UNCHANGED from R11.
__global__ __launch_bounds__(256, 2) void conv_mfma(const ushort* __restrict__ texT,
                                                    const ushort* __restrict__ wbf,
                                                    float* __restrict__ out) {
  extern __shared__ ushort sm[];
  ushort* texs  = sm;            // 20 rows x 18 px x 32 ci = 11520 shorts
  ushort* inter = sm + 11520;    // 18 x 16 x 32 = 9216 + 128 pad
  const int tid = threadIdx.x;
  const int w = tid >> 6, lane = tid & 63;
  const int jn = lane & 15, q = lane >> 4;
  const int tx0 = blockIdx.x * TW, ty0 = blockIdx.y * TH;

  // tex tile -> LDS (quad-swizzle j' = (j+(px>>1))&3), zero outside image
  for (int i = tid; i < 1440; i += 256) {
    int row = i / 72, c = i - row * 72;
    int px = c >> 2, j = c & 3;
    int gy = ty0 - 2 + row, gx = tx0 - 2 + px;
    int4 v; v.x = 0; v.y = 0; v.z = 0; v.w = 0;
    if (gy >= 0 && gy < 256 && gx >= 0 && gx < 256)
      v = ((const int4*)texT)[(gy * 256 + gx) * 4 + j];
    ((int4*)texs)[row * 72 + px * 4 + ((j + (px >> 1)) & 3)] = v;
  }
  __syncthreads();

  // conv1 row starts {0,5,9,13} (rows 9/13 duplicated -> same values, benign);
  // conv2 row starts 4w.
  const int s1 = 4 * w + (w > 0 ? 1 : 0);

  #pragma unroll 1
  for (int bb = 0; bb < NB; ++bb) {
    const int b = blockIdx.z * NB + bb;
    const ushort* wb = wbf + (size_t)b * D_FLT;

    // conv1 A-frags (contiguous 1KB/wave global reads, L2-hot)
    bf16x8 a0[9][2];
    #pragma unroll
    for (int kp = 0; kp < 9; ++kp)
      #pragma unroll
      for (int h = 0; h < 2; ++h)
        a0[kp][h] = *(const bf16x8*)&wb[(kp * 32 + h * 16 + jn) * 32 + q * 8];

    // protect inter while prev batch's conv2 still reads it
    if (bb) __syncthreads();

    // conv1 sliding window: 7 tex rows feed 5 output chains x 2 co-halves
    f32x4 acc[5][2];
    #pragma unroll
    for (int i = 0; i < 5; ++i) {
      acc[i][0] = f32x4{0.f, 0.f, 0.f, 0.f};
      acc[i][1] = f32x4{0.f, 0.f, 0.f, 0.f};
    }
    #pragma unroll
    for (int kyp = 0; kyp < 7; ++kyp) {
      const ushort* trow = &texs[(s1 + kyp) * 576];
      bf16x8 Bf[3];
      #pragma unroll
      for (int kx = 0; kx < 3; ++kx) {
        int p = jn + kx;
        Bf[kx] = *(const bf16x8*)&trow[p * 32 + ((q + (p >> 1)) & 3) * 8];
      }
      #pragma unroll
      for (int i = 0; i < 5; ++i) {
        int ky = kyp - i;
        if (ky >= 0 && ky < 3) {
          #pragma unroll
          for (int kx = 0; kx < 3; ++kx) {
            acc[i][0] = __builtin_amdgcn_mfma_f32_16x16x32_bf16(a0[ky * 3 + kx][0], Bf[kx], acc[i][0], 0, 0, 0);
            acc[i][1] = __builtin_amdgcn_mfma_f32_16x16x32_bf16(a0[ky * 3 + kx][1], Bf[kx], acc[i][1], 0, 0, 0);
          }
        }
      }
    }
    // D: col=lane&15 (pixel), row=(lane>>4)*4+reg (co). Out-of-image inter
    // positions must be EXACT ZERO (reference conv2 zero-pads).
    #pragma unroll
    for (int i = 0; i < 5; ++i) {
      int r = s1 + i;
      int gy1 = ty0 - 1 + r, gx1 = tx0 - 1 + jn;
      bool inimg = (gy1 >= 0 && gy1 < 256 && gx1 >= 0 && gx1 < 256);
      ushort4 p0, p1;
      p0.x = f2bf(lrelu(acc[i][0][0])); p0.y = f2bf(lrelu(acc[i][0][1]));
      p0.z = f2bf(lrelu(acc[i][0][2])); p0.w = f2bf(lrelu(acc[i][0][3]));
      p1.x = f2bf(lrelu(acc[i][1][0])); p1.y = f2bf(lrelu(acc[i][1][1]));
      p1.z = f2bf(lrelu(acc[i][1][2])); p1.w = f2bf(lrelu(acc[i][1][3]));
      if (!inimg) {
        p0.x = p0.y = p0.z = p0.w = 0;
        p1.x = p1.y = p1.z = p1.w = 0;
      }
      int rec = r * 512 + jn * 32;
      int sub = (q & 1) * 4;
      *(ushort4*)&inter[rec + ((((q >> 1) + (jn >> 1)) & 3) * 8) + sub] = p0;
      *(ushort4*)&inter[rec + (((2 + (q >> 1) + (jn >> 1)) & 3) * 8) + sub] = p1;
    }

    // conv2 A-frags loaded HERE (not earlier) to keep conv1 reg peak down;
    // sched_barrier stops the compiler hoisting them above conv1.
    __builtin_amdgcn_sched_barrier(0);
    bf16x8 a1[9];
    #pragma unroll
    for (int kp = 0; kp < 9; ++kp)
      a1[kp] = *(const bf16x8*)&wb[N0Q + (kp * 16 + jn) * 32 + q * 8];
    __syncthreads();

    // conv2 sliding window: 6 inter rows feed 4 output chains; garbage lanes
    // (jn>=TW) read at worst into the 128-short pad and are store-masked.
    {
      const int s2 = 4 * w;
      f32x4 c[4];
      #pragma unroll
      for (int i = 0; i < 4; ++i) c[i] = f32x4{0.f, 0.f, 0.f, 0.f};
      #pragma unroll
      for (int kyp = 0; kyp < 6; ++kyp) {
        const ushort* irow = &inter[(s2 + kyp) * 512];
        bf16x8 Bf[3];
        #pragma unroll
        for (int kx = 0; kx < 3; ++kx) {
          int p = jn + kx;
          Bf[kx] = *(const bf16x8*)&irow[p * 32 + ((q + (p >> 1)) & 3) * 8];
        }
        #pragma unroll
        for (int i = 0; i < 4; ++i) {
          int ky = kyp - i;
          if (ky >= 0 && ky < 3) {
            #pragma unroll
            for (int kx = 0; kx < 3; ++kx)
              c[i] = __builtin_amdgcn_mfma_f32_16x16x32_bf16(a1[ky * 3 + kx], Bf[kx], c[i], 0, 0, 0);
          }
        }
      }
      int gx = tx0 + jn;
      if (jn < TW && gx < 256) {
        #pragma unroll
        for (int i = 0; i < 4; ++i) {
          int gy = ty0 + s2 + i;
          #pragma unroll
          for (int ci = 0; ci < 4; ++ci) {
            int co = q * 4 + ci;
            out[(((size_t)b * 16 + co) * 256 + gy) * 256 + gx] = c[i][ci];
          }
        }
      }
    }
  }
}

extern "C" void kernel_launch(void* const* d_in, const int* in_sizes, int n_in,
                              void* d_out, int out_size, void* d_ws, size_t ws_size,
                              hipStream_t stream) {
  const float* z   = (const float*)d_in[0];
  const float* tex = (const float*)d_in[1];
  const float* W1  = (const float*)d_in[2];
  const float* b1  = (const float*)d_in[3];
  const float* W2  = (const float*)d_in[4];
  const float* b2  = (const float*)d_in[5];
  const float* W3  = (const float*)d_in[6];
  const float* b3  = (const float*)d_in[7];
  float* out = (float*)d_out;

  // ws layout (bytes): h1 [0,32768) | h2 [32768,65536) | wbf bf16 [65536,507904) | texT bf16 [507904,4702208)
  float*  h1   = (float*)d_ws;
  float*  h2   = (float*)((char*)d_ws + 32768);
  ushort* wbf  = (ushort*)((char*)d_ws + 65536);
  ushort* texT = (ushort*)((char*)d_ws + 507904);

  void* args[] = {(void*)&z, (void*)&tex, (void*)&W1, (void*)&b1, (void*)&W2, (void*)&b2,
                  (void*)&W3, (void*)&b3, (void*)&h1, (void*)&h2, (void*)&wbf, (void*)&texT};
  hipLaunchCooperativeKernel((const void*)mlp_coop, dim3(864), dim3(256), args, 0, stream);

  dim3 grid(NTX, 256 / TH, BATCH / NB);
  conv_mfma<<<grid, 256, (11520 + 9216 + 128) * sizeof(ushort), stream>>>(texT, wbf, out);
}

// Round 13
// 111.493 us; speedup vs baseline: 3.7937x; 3.7937x over previous
//
#include <hip/hip_runtime.h>
#include <hip/hip_bf16.h>

#define BATCH 16
#define D_OUT 1024
#define D_HID 512
#define D_FLT 13824
#define N0Q 9216
#define TW 14
#define TH 16
#define NTX 19
#define NB 2

typedef __attribute__((ext_vector_type(8))) short bf16x8;
typedef __attribute__((ext_vector_type(4))) float f32x4;

__device__ __forceinline__ float lrelu(float x) { return x >= 0.f ? x : 0.2f * x; }
__device__ __forceinline__ ushort f2bf(float x) {
  unsigned u = __float_as_uint(x);
  u += 0x7FFFu + ((u >> 16) & 1u);
  return (ushort)(u >> 16);
}

// blocks [0,256): tex fp32 [32][256][256] -> bf16 pixel-major [256*256][32]
// blocks [256,2304): fc1  h1[b][j] = lrelu(z[b]·W1[j] + b1[j])   (R10 version)
__global__ void fc1_tex_kernel(const float* __restrict__ z, const float* __restrict__ W1,
                               const float* __restrict__ b1, float* __restrict__ h1,
                               const float* __restrict__ tex, ushort* __restrict__ texT) {
  int tid = threadIdx.x;
  if (blockIdx.x < 256) {
    int p = blockIdx.x * 256 + tid;
    unsigned pk[16];
    #pragma unroll
    for (int i = 0; i < 16; ++i) {
      ushort lo = f2bf(tex[(2 * i) * 65536 + p]);
      ushort hi = f2bf(tex[(2 * i + 1) * 65536 + p]);
      pk[i] = (unsigned)lo | ((unsigned)hi << 16);
    }
    uint4* dst = (uint4*)&texT[(size_t)p * 32];
    #pragma unroll
    for (int qq = 0; qq < 4; ++qq) {
      uint4 v; v.x = pk[qq * 4]; v.y = pk[qq * 4 + 1]; v.z = pk[qq * 4 + 2]; v.w = pk[qq * 4 + 3];
      dst[qq] = v;
    }
    return;
  }
  int wid = ((blockIdx.x - 256) * 256 + tid) >> 6;
  int lane = tid & 63;
  int b = wid >> 9, j = wid & 511;
  float s = 0.f;
  for (int k = lane; k < D_OUT; k += 64) s += z[b * D_OUT + k] * W1[j * D_OUT + k];
  #pragma unroll
  for (int off = 32; off; off >>= 1) s += __shfl_xor(s, off);
  if (lane == 0) h1[b * 512 + j] = lrelu(s + b1[j]);
}

// fc2 (R10 version): one wave per (b,j).
__global__ void fc2_kernel(const float* __restrict__ in, const float* __restrict__ W,
                           const float* __restrict__ bias, float* __restrict__ out) {
  int wid = (blockIdx.x * blockDim.x + threadIdx.x) >> 6;
  int lane = threadIdx.x & 63;
  int b = wid >> 9, j = wid & 511;
  float s = 0.f;
  for (int k = lane; k < D_HID; k += 64) s += in[b * D_HID + k] * W[j * D_HID + k];
  #pragma unroll
  for (int off = 32; off; off >>= 1) s += __shfl_xor(s, off);
  if (lane == 0) out[b * 512 + j] = lrelu(s + bias[j]);
}

// fc3: 4 j per wave (864 blocks: 4x less hs-staging traffic than 1 j/wave),
// all 16 batches per W3-row read; bf16 filters PERMUTED to conv layout:
// flt0 -> [kpos][co32][ci32], flt1 -> 9216 + [kpos][co16][ci32].
__global__ void fc3_kernel(const float* __restrict__ h2, const float* __restrict__ W3,
                           const float* __restrict__ b3, ushort* __restrict__ wbf) {
  __shared__ float hs[BATCH * D_HID];
  int tid = threadIdx.x;
  for (int i = tid; i < BATCH * D_HID / 4; i += 256)
    ((float4*)hs)[i] = ((const float4*)h2)[i];
  __syncthreads();
  int w = tid >> 6, lane = tid & 63;
  #pragma unroll 1
  for (int jj = 0; jj < 4; ++jj) {
    int j = blockIdx.x * 16 + w * 4 + jj;
    float acc[BATCH];
    #pragma unroll
    for (int b = 0; b < BATCH; ++b) acc[b] = 0.f;
    for (int k = lane; k < D_HID; k += 64) {
      float wv = W3[(size_t)j * D_HID + k];
      #pragma unroll
      for (int b = 0; b < BATCH; ++b) acc[b] += wv * hs[b * D_HID + k];
    }
    #pragma unroll
    for (int b = 0; b < BATCH; ++b) {
      #pragma unroll
      for (int off = 32; off; off >>= 1) acc[b] += __shfl_xor(acc[b], off);
    }
    if (lane == 0) {
      float bb = b3[j];
      int dst;
      if (j < N0Q) {
        int co = j / 288, rem = j - co * 288;
        int ci = rem / 9, kp = rem - ci * 9;
        dst = kp * 1024 + co * 32 + ci;
      } else {
        int t = j - N0Q;
        int co = t / 288, rem = t - co * 288;
        int ci = rem / 9, kp = rem - ci * 9;
        dst = N0Q + kp * 512 + co * 32 + ci;
      }
      #pragma unroll
      for (int b = 0; b < BATCH; ++b) wbf[(size_t)b * D_FLT + dst] = f2bf(acc[b] + bb);
    }
  }
}

// Fused conv1(32->32,3x3,lrelu)+conv2(32->16,3x3), MFMA 16x16x32 bf16.
// Block = 14x16 tile x NB=2 batches. Sliding-window rows (B-reads halved,
// 10/4 independent MFMA chains). (256,2): full VGPR budget, no spill.
// UNCHANGED from R11 (proven: ~70us, VGPR 104, WRITE_SIZE clean 94MB).
__global__ __launch_bounds__(256, 2) void conv_mfma(const ushort* __restrict__ texT,
                                                    const ushort* __restrict__ wbf,
                                                    float* __restrict__ out) {
  extern __shared__ ushort sm[];
  ushort* texs  = sm;            // 20 rows x 18 px x 32 ci = 11520 shorts
  ushort* inter = sm + 11520;    // 18 x 16 x 32 = 9216 + 128 pad
  const int tid = threadIdx.x;
  const int w = tid >> 6, lane = tid & 63;
  const int jn = lane & 15, q = lane >> 4;
  const int tx0 = blockIdx.x * TW, ty0 = blockIdx.y * TH;

  // tex tile -> LDS (quad-swizzle j' = (j+(px>>1))&3), zero outside image
  for (int i = tid; i < 1440; i += 256) {
    int row = i / 72, c = i - row * 72;
    int px = c >> 2, j = c & 3;
    int gy = ty0 - 2 + row, gx = tx0 - 2 + px;
    int4 v; v.x = 0; v.y = 0; v.z = 0; v.w = 0;
    if (gy >= 0 && gy < 256 && gx >= 0 && gx < 256)
      v = ((const int4*)texT)[(gy * 256 + gx) * 4 + j];
    ((int4*)texs)[row * 72 + px * 4 + ((j + (px >> 1)) & 3)] = v;
  }
  __syncthreads();

  // conv1 row starts {0,5,9,13} (rows 9/13 duplicated -> same values, benign);
  // conv2 row starts 4w.
  const int s1 = 4 * w + (w > 0 ? 1 : 0);

  #pragma unroll 1
  for (int bb = 0; bb < NB; ++bb) {
    const int b = blockIdx.z * NB + bb;
    const ushort* wb = wbf + (size_t)b * D_FLT;

    // conv1 A-frags (contiguous 1KB/wave global reads, L2-hot)
    bf16x8 a0[9][2];
    #pragma unroll
    for (int kp = 0; kp < 9; ++kp)
      #pragma unroll
      for (int h = 0; h < 2; ++h)
        a0[kp][h] = *(const bf16x8*)&wb[(kp * 32 + h * 16 + jn) * 32 + q * 8];

    // protect inter while prev batch's conv2 still reads it
    if (bb) __syncthreads();

    // conv1 sliding window: 7 tex rows feed 5 output chains x 2 co-halves
    f32x4 acc[5][2];
    #pragma unroll
    for (int i = 0; i < 5; ++i) {
      acc[i][0] = f32x4{0.f, 0.f, 0.f, 0.f};
      acc[i][1] = f32x4{0.f, 0.f, 0.f, 0.f};
    }
    #pragma unroll
    for (int kyp = 0; kyp < 7; ++kyp) {
      const ushort* trow = &texs[(s1 + kyp) * 576];
      bf16x8 Bf[3];
      #pragma unroll
      for (int kx = 0; kx < 3; ++kx) {
        int p = jn + kx;
        Bf[kx] = *(const bf16x8*)&trow[p * 32 + ((q + (p >> 1)) & 3) * 8];
      }
      #pragma unroll
      for (int i = 0; i < 5; ++i) {
        int ky = kyp - i;
        if (ky >= 0 && ky < 3) {
          #pragma unroll
          for (int kx = 0; kx < 3; ++kx) {
            acc[i][0] = __builtin_amdgcn_mfma_f32_16x16x32_bf16(a0[ky * 3 + kx][0], Bf[kx], acc[i][0], 0, 0, 0);
            acc[i][1] = __builtin_amdgcn_mfma_f32_16x16x32_bf16(a0[ky * 3 + kx][1], Bf[kx], acc[i][1], 0, 0, 0);
          }
        }
      }
    }
    // D: col=lane&15 (pixel), row=(lane>>4)*4+reg (co). Out-of-image inter
    // positions must be EXACT ZERO (reference conv2 zero-pads).
    #pragma unroll
    for (int i = 0; i < 5; ++i) {
      int r = s1 + i;
      int gy1 = ty0 - 1 + r, gx1 = tx0 - 1 + jn;
      bool inimg = (gy1 >= 0 && gy1 < 256 && gx1 >= 0 && gx1 < 256);
      ushort4 p0, p1;
      p0.x = f2bf(lrelu(acc[i][0][0])); p0.y = f2bf(lrelu(acc[i][0][1]));
      p0.z = f2bf(lrelu(acc[i][0][2])); p0.w = f2bf(lrelu(acc[i][0][3]));
      p1.x = f2bf(lrelu(acc[i][1][0])); p1.y = f2bf(lrelu(acc[i][1][1]));
      p1.z = f2bf(lrelu(acc[i][1][2])); p1.w = f2bf(lrelu(acc[i][1][3]));
      if (!inimg) {
        p0.x = p0.y = p0.z = p0.w = 0;
        p1.x = p1.y = p1.z = p1.w = 0;
      }
      int rec = r * 512 + jn * 32;
      int sub = (q & 1) * 4;
      *(ushort4*)&inter[rec + ((((q >> 1) + (jn >> 1)) & 3) * 8) + sub] = p0;
      *(ushort4*)&inter[rec + (((2 + (q >> 1) + (jn >> 1)) & 3) * 8) + sub] = p1;
    }

    // conv2 A-frags loaded HERE (not earlier) to keep conv1 reg peak down;
    // sched_barrier stops the compiler hoisting them above conv1.
    __builtin_amdgcn_sched_barrier(0);
    bf16x8 a1[9];
    #pragma unroll
    for (int kp = 0; kp < 9; ++kp)
      a1[kp] = *(const bf16x8*)&wb[N0Q + (kp * 16 + jn) * 32 + q * 8];
    __syncthreads();

    // conv2 sliding window: 6 inter rows feed 4 output chains; garbage lanes
    // (jn>=TW) read at worst into the 128-short pad and are store-masked.
    {
      const int s2 = 4 * w;
      f32x4 c[4];
      #pragma unroll
      for (int i = 0; i < 4; ++i) c[i] = f32x4{0.f, 0.f, 0.f, 0.f};
      #pragma unroll
      for (int kyp = 0; kyp < 6; ++kyp) {
        const ushort* irow = &inter[(s2 + kyp) * 512];
        bf16x8 Bf[3];
        #pragma unroll
        for (int kx = 0; kx < 3; ++kx) {
          int p = jn + kx;
          Bf[kx] = *(const bf16x8*)&irow[p * 32 + ((q + (p >> 1)) & 3) * 8];
        }
        #pragma unroll
        for (int i = 0; i < 4; ++i) {
          int ky = kyp - i;
          if (ky >= 0 && ky < 3) {
            #pragma unroll
            for (int kx = 0; kx < 3; ++kx)
              c[i] = __builtin_amdgcn_mfma_f32_16x16x32_bf16(a1[ky * 3 + kx], Bf[kx], c[i], 0, 0, 0);
          }
        }
      }
      int gx = tx0 + jn;
      if (jn < TW && gx < 256) {
        #pragma unroll
        for (int i = 0; i < 4; ++i) {
          int gy = ty0 + s2 + i;
          #pragma unroll
          for (int ci = 0; ci < 4; ++ci) {
            int co = q * 4 + ci;
            out[(((size_t)b * 16 + co) * 256 + gy) * 256 + gx] = c[i][ci];
          }
        }
      }
    }
  }
}

extern "C" void kernel_launch(void* const* d_in, const int* in_sizes, int n_in,
                              void* d_out, int out_size, void* d_ws, size_t ws_size,
                              hipStream_t stream) {
  const float* z   = (const float*)d_in[0];
  const float* tex = (const float*)d_in[1];
  const float* W1  = (const float*)d_in[2];
  const float* b1  = (const float*)d_in[3];
  const float* W2  = (const float*)d_in[4];
  const float* b2  = (const float*)d_in[5];
  const float* W3  = (const float*)d_in[6];
  const float* b3  = (const float*)d_in[7];
  float* out = (float*)d_out;

  // ws layout (bytes): h1 [0,32768) | h2 [32768,65536) | wbf bf16 [65536,507904) | texT bf16 [507904,4702208)
  float*  h1   = (float*)d_ws;
  float*  h2   = (float*)((char*)d_ws + 32768);
  ushort* wbf  = (ushort*)((char*)d_ws + 65536);
  ushort* texT = (ushort*)((char*)d_ws + 507904);

  fc1_tex_kernel<<<2304, 256, 0, stream>>>(z, W1, b1, h1, tex, texT);
  fc2_kernel<<<2048, 256, 0, stream>>>(h1, W2, b2, h2);
  fc3_kernel<<<D_FLT / 16, 256, 0, stream>>>(h2, W3, b3, wbf);

  dim3 grid(NTX, 256 / TH, BATCH / NB);
  conv_mfma<<<grid, 256, (11520 + 9216 + 128) * sizeof(ushort), stream>>>(texT, wbf, out);
}